// Round 2
// baseline (4463.850 us; speedup 1.0000x reference)
//
#include <hip/hip_runtime.h>
#include <hip/hip_bf16.h>

// ---------------------------------------------------------------------------
// CirculantAttention on MI355X — round 2: fp32 pipeline, workspace <= 196 MiB.
//
// Round-1 post-mortem: the only unverified assumption was ws_size; round 1
// used 274.7 MB of d_ws. This round restructures to 205,520,896 B:
//   - fft_h (column DFT) runs IN-PLACE (block fully stages its column in LDS
//     before any global write; columns are block-disjoint).
//   - d_out doubles as the real attn scratch (fully overwritten at the end).
//   - conj(A)*v fused into the v-GEMM epilogue (A read+overwritten at the
//     same element by the same thread -> race-free) — v never materialized.
//   - (y .* t) fused into the last inverse-FFT epilogue.
//
// ws layout: T (gate real, 67,108,864 B) | W0 (complex X, 69,206,016 B) |
//            W1 (complex attnf/A/yf, 69,206,016 B)   total 205,520,896 B.
// ---------------------------------------------------------------------------

#define BB 8
#define CC 512
#define HH 64
#define SS 4096   // HH*WW
#define WR 33     // WW/2+1
#define PP 2112   // HH*WR

#define TWOPI_64 0.09817477042468103f   // 2*pi/64

// ========================= GEMM kernels (fp32, tiled) ======================
// Tile: 64 (m) x 16 (n), K-chunk 16, block (16,16), 4 outputs/thread.

__global__ __launch_bounds__(256) void gemm_gate(
    const float* __restrict__ x, const float* __restrict__ wg,
    const float* __restrict__ bg, float* __restrict__ t) {
  __shared__ float As[16][64];
  __shared__ float Ws[16][17];
  int b = blockIdx.z;
  int m0 = blockIdx.x * 64;
  int d0 = blockIdx.y * 16;
  int tx = threadIdx.x, ty = threadIdx.y;
  const float* xb = x + (size_t)b * CC * SS;
  float acc[4] = {0.f, 0.f, 0.f, 0.f};
  for (int k0 = 0; k0 < CC; k0 += 16) {
#pragma unroll
    for (int i = 0; i < 4; ++i)
      As[ty][tx + 16 * i] = xb[(size_t)(k0 + ty) * SS + m0 + tx + 16 * i];
    Ws[ty][tx] = wg[(d0 + ty) * CC + k0 + tx];
    __syncthreads();
#pragma unroll
    for (int kk = 0; kk < 16; ++kk) {
      float w = Ws[ty][kk];
#pragma unroll
      for (int i = 0; i < 4; ++i) acc[i] += As[kk][tx + 16 * i] * w;
    }
    __syncthreads();
  }
  int d = d0 + ty;
  float bias = bg[d];
  size_t ob = ((size_t)b * CC + d) * SS + m0 + tx;
#pragma unroll
  for (int i = 0; i < 4; ++i) {
    float z = acc[i] + bias;
    t[ob + 16 * i] = z / (1.f + __expf(-z));   // SiLU
  }
}

// attnf = conj(q)*k fused: each thread computes q- and k-dots for channel d.
__global__ __launch_bounds__(256) void gemm_qk(
    const float2* __restrict__ X, const float* __restrict__ wqkv,
    float2* __restrict__ attnf) {
  __shared__ float2 As[16][64];
  __shared__ float Wq[16][17];
  __shared__ float Wk[16][17];
  int b = blockIdx.z;
  int m0 = blockIdx.x * 64;
  int d0 = blockIdx.y * 16;
  int tx = threadIdx.x, ty = threadIdx.y;
  const float2* Xb = X + (size_t)b * CC * PP;
  float qr[4] = {0, 0, 0, 0}, qi[4] = {0, 0, 0, 0};
  float kr[4] = {0, 0, 0, 0}, ki[4] = {0, 0, 0, 0};
  for (int k0 = 0; k0 < CC; k0 += 16) {
#pragma unroll
    for (int i = 0; i < 4; ++i)
      As[ty][tx + 16 * i] = Xb[(size_t)(k0 + ty) * PP + m0 + tx + 16 * i];
    Wq[ty][tx] = wqkv[(d0 + ty) * CC + k0 + tx];
    Wk[ty][tx] = wqkv[(CC + d0 + ty) * CC + k0 + tx];
    __syncthreads();
#pragma unroll
    for (int kk = 0; kk < 16; ++kk) {
      float wq = Wq[ty][kk], wk = Wk[ty][kk];
#pragma unroll
      for (int i = 0; i < 4; ++i) {
        float2 a = As[kk][tx + 16 * i];
        qr[i] += a.x * wq; qi[i] += a.y * wq;
        kr[i] += a.x * wk; ki[i] += a.y * wk;
      }
    }
    __syncthreads();
  }
  int d = d0 + ty;
  size_t ob = ((size_t)b * CC + d) * PP + m0 + tx;
#pragma unroll
  for (int i = 0; i < 4; ++i) {
    // conj(q)*k = (qr*kr + qi*ki) + i(qr*ki - qi*kr)
    attnf[ob + 16 * i] =
        make_float2(qr[i] * kr[i] + qi[i] * ki[i], qr[i] * ki[i] - qi[i] * kr[i]);
  }
}

// v-GEMM with fused yf = conj(A)*v epilogue. A is read at the output element
// and overwritten in place (same thread) -> race-free; v never materialized.
__global__ __launch_bounds__(256) void gemm_v_cmul(
    const float2* __restrict__ X, const float* __restrict__ wqkv,
    float2* __restrict__ A_io) {
  __shared__ float2 As[16][64];
  __shared__ float Wv[16][17];
  int b = blockIdx.z;
  int m0 = blockIdx.x * 64;
  int d0 = blockIdx.y * 16;
  int tx = threadIdx.x, ty = threadIdx.y;
  const float2* Xb = X + (size_t)b * CC * PP;
  float vr[4] = {0, 0, 0, 0}, vi[4] = {0, 0, 0, 0};
  for (int k0 = 0; k0 < CC; k0 += 16) {
#pragma unroll
    for (int i = 0; i < 4; ++i)
      As[ty][tx + 16 * i] = Xb[(size_t)(k0 + ty) * PP + m0 + tx + 16 * i];
    Wv[ty][tx] = wqkv[(2 * CC + d0 + ty) * CC + k0 + tx];
    __syncthreads();
#pragma unroll
    for (int kk = 0; kk < 16; ++kk) {
      float wv = Wv[ty][kk];
#pragma unroll
      for (int i = 0; i < 4; ++i) {
        float2 a = As[kk][tx + 16 * i];
        vr[i] += a.x * wv; vi[i] += a.y * wv;
      }
    }
    __syncthreads();
  }
  int d = d0 + ty;
  size_t ob = ((size_t)b * CC + d) * PP + m0 + tx;
#pragma unroll
  for (int i = 0; i < 4; ++i) {
    float2 a = A_io[ob + 16 * i];
    // conj(A)*v = (ar*vr + ai*vi) + i(ar*vi - ai*vr)
    A_io[ob + 16 * i] =
        make_float2(a.x * vr[i] + a.y * vi[i], a.x * vi[i] - a.y * vr[i]);
  }
}

// proj: reads premultiplied (y .* t); epilogue writes planar (b,c,h,w).
__global__ __launch_bounds__(256) void gemm_proj(
    const float* __restrict__ yt, const float* __restrict__ wp,
    const float* __restrict__ bp, float* __restrict__ out) {
  __shared__ float As[16][64];
  __shared__ float Ws[16][17];
  int b = blockIdx.z;
  int m0 = blockIdx.x * 64;
  int d0 = blockIdx.y * 16;
  int tx = threadIdx.x, ty = threadIdx.y;
  size_t base = (size_t)b * CC * SS;
  float acc[4] = {0.f, 0.f, 0.f, 0.f};
  for (int k0 = 0; k0 < CC; k0 += 16) {
#pragma unroll
    for (int i = 0; i < 4; ++i)
      As[ty][tx + 16 * i] = yt[base + (size_t)(k0 + ty) * SS + m0 + tx + 16 * i];
    Ws[ty][tx] = wp[(d0 + ty) * CC + k0 + tx];
    __syncthreads();
#pragma unroll
    for (int kk = 0; kk < 16; ++kk) {
      float w = Ws[ty][kk];
#pragma unroll
      for (int i = 0; i < 4; ++i) acc[i] += As[kk][tx + 16 * i] * w;
    }
    __syncthreads();
  }
  int d = d0 + ty;
  float bias = bp[d];
  size_t ob = base + (size_t)d * SS + m0 + tx;
#pragma unroll
  for (int i = 0; i < 4; ++i) out[ob + 16 * i] = acc[i] + bias;
}

// ========================= DFT kernels (brute-force 64-pt) =================

// real row (64) -> complex (33), forward e^{-i}, unscaled.
__global__ __launch_bounds__(64) void fft_fwd_w(
    const float* __restrict__ in, float2* __restrict__ out) {
  __shared__ float row[64];
  __shared__ float twc[64], tws[64];
  int r = blockIdx.x;
  int t = threadIdx.x;
  row[t] = in[(size_t)r * 64 + t];
  float sv, cv;
  sincosf((float)t * TWOPI_64, &sv, &cv);
  twc[t] = cv; tws[t] = sv;
  __syncthreads();
  if (t < WR) {
    float ar = 0.f, ai = 0.f;
    for (int xx = 0; xx < 64; ++xx) {
      int j = (t * xx) & 63;
      float v = row[xx];
      ar += v * twc[j];
      ai -= v * tws[j];
    }
    out[(size_t)r * WR + t] = make_float2(ar, ai);
  }
}

// complex column DFT along h (stride WR), sign=-1 fwd / +1 inv, * scale.
// SAFE IN-PLACE: full column staged in LDS before any global write.
__global__ __launch_bounds__(64) void fft_h(
    const float2* __restrict__ in, float2* __restrict__ out,
    float sgn, float scale) {
  __shared__ float2 col[64];
  __shared__ float twc[64], tws[64];
  int cid = blockIdx.x;          // bc*WR + kw
  int bc = cid / WR, kw = cid % WR;
  int t = threadIdx.x;
  size_t base = (size_t)bc * PP + kw;
  col[t] = in[base + (size_t)t * WR];
  float sv, cv;
  sincosf((float)t * TWOPI_64, &sv, &cv);
  twc[t] = cv; tws[t] = sv;
  __syncthreads();
  float ar = 0.f, ai = 0.f;
  for (int y = 0; y < 64; ++y) {
    int j = (t * y) & 63;
    float c = twc[j], s = tws[j] * sgn;   // e^{sgn*i*theta} = c + i*s*sgn
    float2 v = col[y];
    ar += v.x * c - v.y * s;
    ai += v.y * c + v.x * s;
  }
  out[base + (size_t)t * WR] = make_float2(ar * scale, ai * scale);
}

// complex row (33, hermitian) -> real row (64), inverse e^{+i}, * scale.
// Optional fused elementwise multiply with tmul (same planar layout).
__global__ __launch_bounds__(64) void fft_inv_w(
    const float2* __restrict__ in, float* __restrict__ out, float scale,
    const float* __restrict__ tmul) {
  __shared__ float2 Sf[WR];
  __shared__ float twc[64], tws[64];
  int r = blockIdx.x;
  int t = threadIdx.x;
  if (t < WR) Sf[t] = in[(size_t)r * WR + t];
  float sv, cv;
  sincosf((float)t * TWOPI_64, &sv, &cv);
  twc[t] = cv; tws[t] = sv;
  __syncthreads();
  float acc = 0.f;
  for (int k = 0; k < 64; ++k) {
    int idx = (k <= 32) ? k : 64 - k;
    float fr = Sf[idx].x;
    float fi = (k <= 32) ? Sf[idx].y : -Sf[idx].y;
    int j = (t * k) & 63;
    acc += fr * twc[j] - fi * tws[j];   // Re{F[k] e^{+i theta}}
  }
  size_t o = (size_t)r * 64 + t;
  float res = acc * scale;
  if (tmul) res *= tmul[o];
  out[o] = res;
}

// ========================= softmax over n per (b,c) ========================
__global__ __launch_bounds__(256) void softmax_n(float* __restrict__ a) {
  __shared__ float red[16];
  int bc = blockIdx.x;
  float* p = a + (size_t)bc * SS;
  int t = threadIdx.x;
  float m = -1e30f;
  for (int i = t; i < SS; i += 256) m = fmaxf(m, p[i]);
#pragma unroll
  for (int off = 32; off > 0; off >>= 1) m = fmaxf(m, __shfl_down(m, off));
  if ((t & 63) == 0) red[t >> 6] = m;
  __syncthreads();
  if (t == 0) red[0] = fmaxf(fmaxf(red[0], red[1]), fmaxf(red[2], red[3]));
  __syncthreads();
  m = red[0];
  float s = 0.f;
  for (int i = t; i < SS; i += 256) s += __expf(p[i] - m);
#pragma unroll
  for (int off = 32; off > 0; off >>= 1) s += __shfl_down(s, off);
  if ((t & 63) == 0) red[8 + (t >> 6)] = s;
  __syncthreads();
  if (t == 0) red[4] = red[8] + red[9] + red[10] + red[11];
  __syncthreads();
  float inv = 1.f / red[4];
  for (int i = t; i < SS; i += 256) p[i] = __expf(p[i] - m) * inv;
}

// ===========================================================================
extern "C" void kernel_launch(void* const* d_in, const int* in_sizes, int n_in,
                              void* d_out, int out_size, void* d_ws, size_t ws_size,
                              hipStream_t stream) {
  const float* x      = (const float*)d_in[0];
  const float* w_qkv  = (const float*)d_in[1];
  const float* w_gate = (const float*)d_in[2];
  const float* b_gate = (const float*)d_in[3];
  const float* w_proj = (const float*)d_in[4];
  const float* b_proj = (const float*)d_in[5];
  float* out = (float*)d_out;

  char* ws = (char*)d_ws;
  float*  T  = (float*)ws;                             // 67,108,864 B
  float2* W0 = (float2*)(ws + 67108864);               // 69,206,016 B
  float2* W1 = (float2*)(ws + 136314880);              // 69,206,016 B (end 205,520,896)

  dim3 gblk(16, 16);
  dim3 gemmS(SS / 64, CC / 16, BB);   // spatial-4096 GEMMs
  dim3 gemmP(PP / 64, CC / 16, BB);   // freq-2112 GEMMs
  const int ROWS = BB * CC * HH;      // 262144
  const int COLS = BB * CC * WR;      // 135168
  const float INV64 = 1.f / 64.f;

  // 1. gate: t = silu(x @ w_gate^T + b_gate)  [planar]
  gemm_gate<<<gemmS, gblk, 0, stream>>>(x, w_gate, b_gate, T);
  // 2-3. X = rfft2(x, ortho): w-pass unscaled, h-pass 1/64 (in-place).
  fft_fwd_w<<<ROWS, 64, 0, stream>>>(x, W0);
  fft_h<<<COLS, 64, 0, stream>>>(W0, W0, -1.f, INV64);           // X in W0
  // 4. attnf = conj(q)*k
  gemm_qk<<<gemmP, gblk, 0, stream>>>(W0, w_qkv, W1);            // attnf in W1
  // 5-6. attn = irfft2(attnf, ortho) -> d_out (real scratch)
  fft_h<<<COLS, 64, 0, stream>>>(W1, W1, +1.f, 1.f);
  fft_inv_w<<<ROWS, 64, 0, stream>>>(W1, out, INV64, nullptr);   // attn in d_out
  // 7. softmax over n per (b,c), in-place on d_out
  softmax_n<<<BB * CC, 256, 0, stream>>>(out);
  // 8-9. A = rfft2(attn) backward norm (UNSCALED)
  fft_fwd_w<<<ROWS, 64, 0, stream>>>(out, W1);
  fft_h<<<COLS, 64, 0, stream>>>(W1, W1, -1.f, 1.f);             // A in W1
  // 10. v-GEMM fused with yf = conj(A)*v, in-place on W1
  gemm_v_cmul<<<gemmP, gblk, 0, stream>>>(W0, w_qkv, W1);        // yf in W1
  // 11-12. y = irfft2(yf, ortho), fused (.* t) -> W0 reused as real buffer
  fft_h<<<COLS, 64, 0, stream>>>(W1, W1, +1.f, 1.f);
  fft_inv_w<<<ROWS, 64, 0, stream>>>(W1, (float*)W0, INV64, T);  // y.*t in W0
  // 13. out = (y .* t) @ w_proj^T + b_proj   [planar epilogue]
  gemm_proj<<<gemmS, gblk, 0, stream>>>((const float*)W0, w_proj, b_proj, out);
}

// Round 3
// 2345.877 us; speedup vs baseline: 1.9028x; 1.9028x over previous
//
#include <hip/hip_runtime.h>
#include <hip/hip_bf16.h>

// ---------------------------------------------------------------------------
// CirculantAttention on MI355X — round 3: GEMMs -> bf16x2 MFMA emulation.
//
// GEMM math: D[m][d] = sum_c Act[c][m] * W[d][c], fp32 split into hi/lo bf16
// (3 MFMAs per 32-K block: hh + hl + lh; lo*lo term ~2^-16 negligible).
// MFMA mfma_f32_16x16x32_bf16, A-op = Act^T fragment (row=lane&15=m,
// k=(lane>>4)*8+j contiguous), B-op = W fragment (col=lane&15=d, same k),
// D row=(lane>>4)*4+reg, col=lane&15  [per verified m89/m91 layouts].
//
// Staging per K-step: global_load_lds fp32 tile [32c][64m] -> LDS raw;
// transpose pass splits to bf16 hi/lo planes [64m][32c] with XOR-swizzled
// 16B chunks (chunk' = chunk ^ (m&3)) so ds_read_b128 fragments stay ~4-way.
// Weights pre-split ONCE per launch into global bf16 hi/lo planes (prep_w).
//
// ws layout: T 67,108,864 | W0 69,206,016 | W1 69,206,016 | Wplanes 7,340,032
//            total 212,860,928 B  (round-2's 205.5 MB passed; <256 MiB).
// ---------------------------------------------------------------------------

#define BB 8
#define CC 512
#define HH 64
#define SS 4096   // HH*WW
#define WR 33     // WW/2+1
#define PP 2112   // HH*WR

#define TWOPI_64 0.09817477042468103f   // 2*pi/64

typedef float f32x4 __attribute__((ext_vector_type(4)));
typedef __bf16 bf16x8 __attribute__((ext_vector_type(8)));
typedef unsigned short ushort;
typedef ushort ushort8 __attribute__((ext_vector_type(8)));

// ushort-unit offsets inside the weight-plane arena
#define QKV_HI 0
#define QKV_LO 786432
#define GATE_HI 1572864
#define GATE_LO 2097152
#define PROJ_HI 2621440
#define PROJ_LO 3145728
#define PLANES_USHORTS 3670016   // 7,340,032 bytes

__device__ __forceinline__ void split2(float x, ushort& h, ushort& l) {
  unsigned bx = __builtin_bit_cast(unsigned, x);
  h = (ushort)(bx >> 16);
  float hf = __builtin_bit_cast(float, bx & 0xffff0000u);
  float lf = x - hf;
  l = (ushort)(__builtin_bit_cast(unsigned, lf) >> 16);
}

__device__ __forceinline__ void gll16(const float* src, float* lds_dst) {
  __builtin_amdgcn_global_load_lds(
      (const __attribute__((address_space(1))) unsigned int*)src,
      (__attribute__((address_space(3))) unsigned int*)lds_dst, 16, 0, 0);
}

// ===================== weight pre-split (once per launch) ==================
__global__ __launch_bounds__(256) void prep_w(
    const float* __restrict__ wqkv, const float* __restrict__ wg,
    const float* __restrict__ wp, ushort* __restrict__ planes) {
  int i = blockIdx.x * 256 + threadIdx.x;   // 0 .. 1,310,719
  float v; ushort *hp, *lp;
  if (i < 786432) {
    v = wqkv[i]; hp = planes + QKV_HI + i; lp = planes + QKV_LO + i;
  } else if (i < 1048576) {
    int j = i - 786432;
    v = wg[j]; hp = planes + GATE_HI + j; lp = planes + GATE_LO + j;
  } else {
    int j = i - 1048576;
    v = wp[j]; hp = planes + PROJ_HI + j; lp = planes + PROJ_LO + j;
  }
  ushort h, l; split2(v, h, l);
  *hp = h; *lp = l;
}

// ===================== real-activation GEMM (gate / proj) ==================
// MODE 0: gate  (epilogue silu(z+bias))   MODE 1: proj (z+bias)
template <int MODE>
__global__ __launch_bounds__(256) void gemm_real(
    const float* __restrict__ act,        // [BB][CC][SS] planar
    const ushort* __restrict__ w_hi, const ushort* __restrict__ w_lo,
    const float* __restrict__ bias, float* __restrict__ outp) {
  __shared__ float raw[32 * 64];          // [c][m] fp32
  __shared__ ushort planeH[64 * 32];      // [m][c] bf16-hi, 16B-chunk swizzled
  __shared__ ushort planeL[64 * 32];
  int b = blockIdx.z;
  int m0 = blockIdx.x * 64;
  int d0 = blockIdx.y * 64;
  int tid = threadIdx.x;
  int lane = tid & 63, wid = tid >> 6;
  int fr = lane & 15, fq = lane >> 4;
  int wm = wid & 1, wd = wid >> 1;
  int co = tid >> 6, tm = tid & 63;       // transpose-pass ids
  const float* actb = act + (size_t)b * CC * SS + m0;

  f32x4 acc[2][2] = {};                   // [mt][dt]

  for (int k0 = 0; k0 < CC; k0 += 32) {
    // ---- stage raw tile (2048 f32) via global_load_lds width 16 ----
#pragma unroll
    for (int i = 0; i < 2; ++i) {
      int e0 = (i * 256 + tid) * 4;       // f32 index in tile
      int c = e0 >> 6, m = e0 & 63;
      gll16(actb + (size_t)(k0 + c) * SS + m, raw + (i * 256 + (tid & 192)) * 4);
    }
    __syncthreads();                      // drains vmcnt + barrier
    // ---- transpose + split to bf16 planes ----
    {
      ushort h[8], l[8];
#pragma unroll
      for (int j = 0; j < 8; ++j) split2(raw[(co * 8 + j) * 64 + tm], h[j], l[j]);
      int ch = ((co ^ (tm & 3)) * 8);
      ushort8 vh, vl;
#pragma unroll
      for (int j = 0; j < 8; ++j) { vh[j] = h[j]; vl[j] = l[j]; }
      *reinterpret_cast<ushort8*>(&planeH[tm * 32 + ch]) = vh;
      *reinterpret_cast<ushort8*>(&planeL[tm * 32 + ch]) = vl;
    }
    __syncthreads();
    // ---- fragments + MFMA ----
    bf16x8 wfh[2], wfl[2], afh[2], afl[2];
#pragma unroll
    for (int dt = 0; dt < 2; ++dt) {
      int d = d0 + wd * 32 + dt * 16 + fr;
      size_t wo = (size_t)d * CC + k0 + fq * 8;
      wfh[dt] = *reinterpret_cast<const bf16x8*>(&w_hi[wo]);
      wfl[dt] = *reinterpret_cast<const bf16x8*>(&w_lo[wo]);
    }
#pragma unroll
    for (int mt = 0; mt < 2; ++mt) {
      int m = wm * 32 + mt * 16 + fr;
      int ch = (fq ^ (m & 3)) * 8;
      afh[mt] = *reinterpret_cast<const bf16x8*>(&planeH[m * 32 + ch]);
      afl[mt] = *reinterpret_cast<const bf16x8*>(&planeL[m * 32 + ch]);
    }
#pragma unroll
    for (int mt = 0; mt < 2; ++mt)
#pragma unroll
      for (int dt = 0; dt < 2; ++dt) {
        acc[mt][dt] = __builtin_amdgcn_mfma_f32_16x16x32_bf16(afh[mt], wfh[dt], acc[mt][dt], 0, 0, 0);
        acc[mt][dt] = __builtin_amdgcn_mfma_f32_16x16x32_bf16(afh[mt], wfl[dt], acc[mt][dt], 0, 0, 0);
        acc[mt][dt] = __builtin_amdgcn_mfma_f32_16x16x32_bf16(afl[mt], wfh[dt], acc[mt][dt], 0, 0, 0);
      }
  }
  // ---- epilogue ----
#pragma unroll
  for (int mt = 0; mt < 2; ++mt)
#pragma unroll
    for (int dt = 0; dt < 2; ++dt) {
      int d = d0 + wd * 32 + dt * 16 + fr;
      float bs = bias[d];
      size_t ob = ((size_t)b * CC + d) * SS + m0 + wm * 32 + mt * 16 + fq * 4;
#pragma unroll
      for (int r = 0; r < 4; ++r) {
        float z = acc[mt][dt][r] + bs;
        if (MODE == 0) z = z / (1.f + __expf(-z));   // SiLU
        outp[ob + r] = z;
      }
    }
}

// ===================== complex-activation GEMM (qk / v) ====================
// MODE 0: qk — two weight mats, epilogue attnf = conj(q)*k
// MODE 1: v  — one weight mat, epilogue A_io = conj(A)*v (in place)
template <int MODE>
__global__ __launch_bounds__(256) void gemm_cplx(
    const float2* __restrict__ X,         // [BB][CC][PP] planar complex
    const ushort* __restrict__ w1_hi, const ushort* __restrict__ w1_lo,
    const ushort* __restrict__ w2_hi, const ushort* __restrict__ w2_lo,
    float2* __restrict__ io) {            // qk: out attnf; v: in/out A
  __shared__ float raw[32 * 128];         // [c][m] float2 (as f32 pairs)
  __shared__ ushort pRH[64 * 32];         // re-hi [m][c], swizzled chunks
  __shared__ ushort pRL[64 * 32];
  __shared__ ushort pIH[64 * 32];
  __shared__ ushort pIL[64 * 32];
  int b = blockIdx.z;
  int m0 = blockIdx.x * 64;
  int d0 = blockIdx.y * 64;
  int tid = threadIdx.x;
  int lane = tid & 63, wid = tid >> 6;
  int fr = lane & 15, fq = lane >> 4;
  int wm = wid & 1, wd = wid >> 1;
  int co = tid >> 6, tm = tid & 63;
  const float* actf = (const float*)(X + (size_t)b * CC * PP + m0);

  // acc[mt][dt][combo]; qk: 0=q·re 1=q·im 2=k·re 3=k·im ; v: 0=v·re 1=v·im
  f32x4 acc[2][2][MODE == 0 ? 4 : 2] = {};

  for (int k0 = 0; k0 < CC; k0 += 32) {
    // ---- stage raw tile (32c x 64m complex = 4096 f32) ----
#pragma unroll
    for (int i = 0; i < 4; ++i) {
      int e0 = (i * 256 + tid) * 4;
      int c = e0 >> 7, r128 = e0 & 127;
      gll16(actf + (size_t)(k0 + c) * PP * 2 + r128,
            raw + (i * 256 + (tid & 192)) * 4);
    }
    __syncthreads();
    // ---- transpose + split ----
    {
      const float2* raw2 = (const float2*)raw;
      ushort rh[8], rl[8], ih[8], il[8];
#pragma unroll
      for (int j = 0; j < 8; ++j) {
        float2 v = raw2[(co * 8 + j) * 64 + tm];
        split2(v.x, rh[j], rl[j]);
        split2(v.y, ih[j], il[j]);
      }
      int ch = ((co ^ (tm & 3)) * 8);
      ushort8 vrh, vrl, vih, vil;
#pragma unroll
      for (int j = 0; j < 8; ++j) { vrh[j] = rh[j]; vrl[j] = rl[j]; vih[j] = ih[j]; vil[j] = il[j]; }
      *reinterpret_cast<ushort8*>(&pRH[tm * 32 + ch]) = vrh;
      *reinterpret_cast<ushort8*>(&pRL[tm * 32 + ch]) = vrl;
      *reinterpret_cast<ushort8*>(&pIH[tm * 32 + ch]) = vih;
      *reinterpret_cast<ushort8*>(&pIL[tm * 32 + ch]) = vil;
    }
    __syncthreads();
    // ---- fragments ----
    bf16x8 w1h[2], w1l[2], w2h[2], w2l[2];
    bf16x8 arh[2], arl[2], aih[2], ail[2];
#pragma unroll
    for (int dt = 0; dt < 2; ++dt) {
      int d = d0 + wd * 32 + dt * 16 + fr;
      size_t wo = (size_t)d * CC + k0 + fq * 8;
      w1h[dt] = *reinterpret_cast<const bf16x8*>(&w1_hi[wo]);
      w1l[dt] = *reinterpret_cast<const bf16x8*>(&w1_lo[wo]);
      if (MODE == 0) {
        w2h[dt] = *reinterpret_cast<const bf16x8*>(&w2_hi[wo]);
        w2l[dt] = *reinterpret_cast<const bf16x8*>(&w2_lo[wo]);
      }
    }
#pragma unroll
    for (int mt = 0; mt < 2; ++mt) {
      int m = wm * 32 + mt * 16 + fr;
      int ch = (fq ^ (m & 3)) * 8;
      arh[mt] = *reinterpret_cast<const bf16x8*>(&pRH[m * 32 + ch]);
      arl[mt] = *reinterpret_cast<const bf16x8*>(&pRL[m * 32 + ch]);
      aih[mt] = *reinterpret_cast<const bf16x8*>(&pIH[m * 32 + ch]);
      ail[mt] = *reinterpret_cast<const bf16x8*>(&pIL[m * 32 + ch]);
    }
    // ---- MFMAs: combo = weight x (re|im), 3 products each ----
#pragma unroll
    for (int mt = 0; mt < 2; ++mt)
#pragma unroll
      for (int dt = 0; dt < 2; ++dt) {
        acc[mt][dt][0] = __builtin_amdgcn_mfma_f32_16x16x32_bf16(arh[mt], w1h[dt], acc[mt][dt][0], 0, 0, 0);
        acc[mt][dt][0] = __builtin_amdgcn_mfma_f32_16x16x32_bf16(arh[mt], w1l[dt], acc[mt][dt][0], 0, 0, 0);
        acc[mt][dt][0] = __builtin_amdgcn_mfma_f32_16x16x32_bf16(arl[mt], w1h[dt], acc[mt][dt][0], 0, 0, 0);
        acc[mt][dt][1] = __builtin_amdgcn_mfma_f32_16x16x32_bf16(aih[mt], w1h[dt], acc[mt][dt][1], 0, 0, 0);
        acc[mt][dt][1] = __builtin_amdgcn_mfma_f32_16x16x32_bf16(aih[mt], w1l[dt], acc[mt][dt][1], 0, 0, 0);
        acc[mt][dt][1] = __builtin_amdgcn_mfma_f32_16x16x32_bf16(ail[mt], w1h[dt], acc[mt][dt][1], 0, 0, 0);
        if (MODE == 0) {
          acc[mt][dt][2] = __builtin_amdgcn_mfma_f32_16x16x32_bf16(arh[mt], w2h[dt], acc[mt][dt][2], 0, 0, 0);
          acc[mt][dt][2] = __builtin_amdgcn_mfma_f32_16x16x32_bf16(arh[mt], w2l[dt], acc[mt][dt][2], 0, 0, 0);
          acc[mt][dt][2] = __builtin_amdgcn_mfma_f32_16x16x32_bf16(arl[mt], w2h[dt], acc[mt][dt][2], 0, 0, 0);
          acc[mt][dt][3] = __builtin_amdgcn_mfma_f32_16x16x32_bf16(aih[mt], w2h[dt], acc[mt][dt][3], 0, 0, 0);
          acc[mt][dt][3] = __builtin_amdgcn_mfma_f32_16x16x32_bf16(aih[mt], w2l[dt], acc[mt][dt][3], 0, 0, 0);
          acc[mt][dt][3] = __builtin_amdgcn_mfma_f32_16x16x32_bf16(ail[mt], w2h[dt], acc[mt][dt][3], 0, 0, 0);
        }
      }
  }
  // ---- epilogue ----
#pragma unroll
  for (int mt = 0; mt < 2; ++mt)
#pragma unroll
    for (int dt = 0; dt < 2; ++dt) {
      int d = d0 + wd * 32 + dt * 16 + fr;
      size_t ob = ((size_t)b * CC + d) * PP + m0 + wm * 32 + mt * 16 + fq * 4;
#pragma unroll
      for (int r = 0; r < 4; ++r) {
        if (MODE == 0) {
          float qr = acc[mt][dt][0][r], qi = acc[mt][dt][1][r];
          float kr = acc[mt][dt][2][r], ki = acc[mt][dt][3][r];
          io[ob + r] = make_float2(qr * kr + qi * ki, qr * ki - qi * kr);
        } else {
          float vr = acc[mt][dt][0][r], vi = acc[mt][dt][1][r];
          float2 a = io[ob + r];
          io[ob + r] = make_float2(a.x * vr + a.y * vi, a.x * vi - a.y * vr);
        }
      }
    }
}

// ========================= DFT kernels (brute-force 64-pt) =================

__global__ __launch_bounds__(64) void fft_fwd_w(
    const float* __restrict__ in, float2* __restrict__ out) {
  __shared__ float row[64];
  __shared__ float twc[64], tws[64];
  int r = blockIdx.x;
  int t = threadIdx.x;
  row[t] = in[(size_t)r * 64 + t];
  float sv, cv;
  sincosf((float)t * TWOPI_64, &sv, &cv);
  twc[t] = cv; tws[t] = sv;
  __syncthreads();
  if (t < WR) {
    float ar = 0.f, ai = 0.f;
    for (int xx = 0; xx < 64; ++xx) {
      int j = (t * xx) & 63;
      float v = row[xx];
      ar += v * twc[j];
      ai -= v * tws[j];
    }
    out[(size_t)r * WR + t] = make_float2(ar, ai);
  }
}

// in-place safe: full column staged in LDS before any global write.
__global__ __launch_bounds__(64) void fft_h(
    const float2* __restrict__ in, float2* __restrict__ out,
    float sgn, float scale) {
  __shared__ float2 col[64];
  __shared__ float twc[64], tws[64];
  int cid = blockIdx.x;          // bc*WR + kw
  int bc = cid / WR, kw = cid % WR;
  int t = threadIdx.x;
  size_t base = (size_t)bc * PP + kw;
  col[t] = in[base + (size_t)t * WR];
  float sv, cv;
  sincosf((float)t * TWOPI_64, &sv, &cv);
  twc[t] = cv; tws[t] = sv;
  __syncthreads();
  float ar = 0.f, ai = 0.f;
  for (int y = 0; y < 64; ++y) {
    int j = (t * y) & 63;
    float c = twc[j], s = tws[j] * sgn;
    float2 v = col[y];
    ar += v.x * c - v.y * s;
    ai += v.y * c + v.x * s;
  }
  out[base + (size_t)t * WR] = make_float2(ar * scale, ai * scale);
}

__global__ __launch_bounds__(64) void fft_inv_w(
    const float2* __restrict__ in, float* __restrict__ out, float scale,
    const float* __restrict__ tmul) {
  __shared__ float2 Sf[WR];
  __shared__ float twc[64], tws[64];
  int r = blockIdx.x;
  int t = threadIdx.x;
  if (t < WR) Sf[t] = in[(size_t)r * WR + t];
  float sv, cv;
  sincosf((float)t * TWOPI_64, &sv, &cv);
  twc[t] = cv; tws[t] = sv;
  __syncthreads();
  float acc = 0.f;
  for (int k = 0; k < 64; ++k) {
    int idx = (k <= 32) ? k : 64 - k;
    float fr = Sf[idx].x;
    float fi = (k <= 32) ? Sf[idx].y : -Sf[idx].y;
    int j = (t * k) & 63;
    acc += fr * twc[j] - fi * tws[j];
  }
  size_t o = (size_t)r * 64 + t;
  float res = acc * scale;
  if (tmul) res *= tmul[o];
  out[o] = res;
}

// ========================= softmax over n per (b,c) ========================
__global__ __launch_bounds__(256) void softmax_n(float* __restrict__ a) {
  __shared__ float red[16];
  int bc = blockIdx.x;
  float* p = a + (size_t)bc * SS;
  int t = threadIdx.x;
  float m = -1e30f;
  for (int i = t; i < SS; i += 256) m = fmaxf(m, p[i]);
#pragma unroll
  for (int off = 32; off > 0; off >>= 1) m = fmaxf(m, __shfl_down(m, off));
  if ((t & 63) == 0) red[t >> 6] = m;
  __syncthreads();
  if (t == 0) red[0] = fmaxf(fmaxf(red[0], red[1]), fmaxf(red[2], red[3]));
  __syncthreads();
  m = red[0];
  float s = 0.f;
  for (int i = t; i < SS; i += 256) s += __expf(p[i] - m);
#pragma unroll
  for (int off = 32; off > 0; off >>= 1) s += __shfl_down(s, off);
  if ((t & 63) == 0) red[8 + (t >> 6)] = s;
  __syncthreads();
  if (t == 0) red[4] = red[8] + red[9] + red[10] + red[11];
  __syncthreads();
  float inv = 1.f / red[4];
  for (int i = t; i < SS; i += 256) p[i] = __expf(p[i] - m) * inv;
}

// ===========================================================================
extern "C" void kernel_launch(void* const* d_in, const int* in_sizes, int n_in,
                              void* d_out, int out_size, void* d_ws, size_t ws_size,
                              hipStream_t stream) {
  const float* x      = (const float*)d_in[0];
  const float* w_qkv  = (const float*)d_in[1];
  const float* w_gate = (const float*)d_in[2];
  const float* b_gate = (const float*)d_in[3];
  const float* w_proj = (const float*)d_in[4];
  const float* b_proj = (const float*)d_in[5];
  float* out = (float*)d_out;

  char* ws = (char*)d_ws;
  float*  T  = (float*)ws;                             // 67,108,864 B
  float2* W0 = (float2*)(ws + 67108864);               // 69,206,016 B
  float2* W1 = (float2*)(ws + 136314880);              // 69,206,016 B
  ushort* PL = (ushort*)(ws + 205520896);              //  7,340,032 B (end 212,860,928)

  dim3 gemmS(SS / 64, CC / 64, BB);   // (64, 8, 8)
  dim3 gemmP(PP / 64, CC / 64, BB);   // (33, 8, 8)
  const int ROWS = BB * CC * HH;      // 262144
  const int COLS = BB * CC * WR;      // 135168
  const float INV64 = 1.f / 64.f;

  // 0. weight split to bf16 hi/lo planes
  prep_w<<<1310720 / 256, 256, 0, stream>>>(w_qkv, w_gate, w_proj, PL);
  // 1. gate: t = silu(x @ w_gate^T + b_gate)
  gemm_real<0><<<gemmS, 256, 0, stream>>>(x, PL + GATE_HI, PL + GATE_LO, b_gate, T);
  // 2-3. X = rfft2(x, ortho)
  fft_fwd_w<<<ROWS, 64, 0, stream>>>(x, W0);
  fft_h<<<COLS, 64, 0, stream>>>(W0, W0, -1.f, INV64);            // X in W0
  // 4. attnf = conj(q)*k
  gemm_cplx<0><<<gemmP, 256, 0, stream>>>(W0, PL + QKV_HI, PL + QKV_LO,
                                          PL + QKV_HI + CC * CC, PL + QKV_LO + CC * CC, W1);
  // 5-6. attn = irfft2(attnf, ortho) -> d_out
  fft_h<<<COLS, 64, 0, stream>>>(W1, W1, +1.f, 1.f);
  fft_inv_w<<<ROWS, 64, 0, stream>>>(W1, out, INV64, nullptr);
  // 7. softmax over n per (b,c)
  softmax_n<<<BB * CC, 256, 0, stream>>>(out);
  // 8-9. A = rfft2(attn), backward norm (unscaled)
  fft_fwd_w<<<ROWS, 64, 0, stream>>>(out, W1);
  fft_h<<<COLS, 64, 0, stream>>>(W1, W1, -1.f, 1.f);              // A in W1
  // 10. v-GEMM fused with yf = conj(A)*v (in place on W1)
  gemm_cplx<1><<<gemmP, 256, 0, stream>>>(W0, PL + QKV_HI + 2 * CC * CC, PL + QKV_LO + 2 * CC * CC,
                                          nullptr, nullptr, W1);
  // 11-12. y = irfft2(yf, ortho), fused (.* t) -> W0 (real)
  fft_h<<<COLS, 64, 0, stream>>>(W1, W1, +1.f, 1.f);
  fft_inv_w<<<ROWS, 64, 0, stream>>>(W1, (float*)W0, INV64, T);
  // 13. out = (y .* t) @ w_proj^T + b_proj
  gemm_real<1><<<gemmS, 256, 0, stream>>>((const float*)W0, PL + PROJ_HI, PL + PROJ_LO, b_proj, out);
}

// Round 4
// 1107.383 us; speedup vs baseline: 4.0310x; 2.1184x over previous
//
#include <hip/hip_runtime.h>
#include <hip/hip_bf16.h>

// ---------------------------------------------------------------------------
// CirculantAttention on MI355X — round 4: DFTs -> bf16x2 twiddle MFMA GEMMs.
//
// All 64-pt DFT passes are matmuls by fixed twiddle matrices:
//   dftw_fwd : real[M][64]  @ TWF[64][66p80]  -> cplx-interleaved [M][66]
//   dfth     : [M][128]     @ TWH[128][128]   -> [M][128] (re/im 2x2 blocks),
//              IN-PLACE (wave loads its 16 full rows to regs before stores)
//   dftw_inv : cplx[M][66]  @ TWI[66->64][64] -> real[M][64]; kw=32 term is a
//              fr32*(-1)^x/64 epilogue add; optional fused (.* t)
// bf16x2 split (hh+hl+lh MFMAs) on both operands, as validated in round 3.
// Twiddle planes precomputed to ws (prep_tw), staged to LDS per block; row
// stride = odd multiple of 16B => ~2-way bank conflicts (free).
//
// ws: T 67,108,864 | W0 69,206,016 | W1 69,206,016 | PL 7,340,032 |
//     TW 253,952   => total 213,114,880 B (round-3's 212.9 MB passed).
// ---------------------------------------------------------------------------

#define BB 8
#define CC 512
#define HH 64
#define SS 4096   // HH*WW
#define WR 33     // WW/2+1
#define PP 2112   // HH*WR

#define TWOPI_64 0.09817477042468103f   // 2*pi/64

typedef float f32x4 __attribute__((ext_vector_type(4)));
typedef __bf16 bf16x8 __attribute__((ext_vector_type(8)));
typedef unsigned short ushort;
typedef ushort ushort8 __attribute__((ext_vector_type(8)));

// ushort-unit offsets inside the GEMM weight-plane arena
#define QKV_HI 0
#define QKV_LO 786432
#define GATE_HI 1572864
#define GATE_LO 2097152
#define PROJ_HI 2621440
#define PROJ_LO 3145728

// ushort-unit offsets inside the twiddle arena
#define TWF_OFF 0         // [80][72] hi + lo (5760 each), arena 12288
#define TWH0_OFF 12288    // fwd, scale 1/64   [128][136] hi+lo (17408 each)
#define TWH1_OFF 47104    // inv, scale 1
#define TWH2_OFF 81920    // fwd, scale 1
#define TWI_OFF 116736    // [64][72] hi+lo (4608 each), arena 10240
#define TW_USHORTS 126976 // 253,952 bytes

__device__ __forceinline__ void split2(float x, ushort& h, ushort& l) {
  unsigned bx = __builtin_bit_cast(unsigned, x);
  h = (ushort)(bx >> 16);
  float hf = __builtin_bit_cast(float, bx & 0xffff0000u);
  float lf = x - hf;
  l = (ushort)(__builtin_bit_cast(unsigned, lf) >> 16);
}

__device__ __forceinline__ void gll16(const void* src, void* lds_dst) {
  __builtin_amdgcn_global_load_lds(
      (const __attribute__((address_space(1))) unsigned int*)src,
      (__attribute__((address_space(3))) unsigned int*)lds_dst, 16, 0, 0);
}

#define MFMA16(a, b, c) __builtin_amdgcn_mfma_f32_16x16x32_bf16(a, b, c, 0, 0, 0)

__device__ __forceinline__ void pack8(const float* f, bf16x8& hi, bf16x8& lo) {
  ushort8 hs, ls;
#pragma unroll
  for (int j = 0; j < 8; ++j) { ushort h, l; split2(f[j], h, l); hs[j] = h; ls[j] = l; }
  hi = __builtin_bit_cast(bf16x8, hs);
  lo = __builtin_bit_cast(bf16x8, ls);
}

// ===================== weight pre-split (once per launch) ==================
__global__ __launch_bounds__(256) void prep_w(
    const float* __restrict__ wqkv, const float* __restrict__ wg,
    const float* __restrict__ wp, ushort* __restrict__ planes) {
  int i = blockIdx.x * 256 + threadIdx.x;   // 0 .. 1,310,719
  float v; ushort *hp, *lp;
  if (i < 786432) {
    v = wqkv[i]; hp = planes + QKV_HI + i; lp = planes + QKV_LO + i;
  } else if (i < 1048576) {
    int j = i - 786432;
    v = wg[j]; hp = planes + GATE_HI + j; lp = planes + GATE_LO + j;
  } else {
    int j = i - 1048576;
    v = wp[j]; hp = planes + PROJ_HI + j; lp = planes + PROJ_LO + j;
  }
  ushort h, l; split2(v, h, l);
  *hp = h; *lp = l;
}

// ===================== twiddle pre-split (once per launch) =================
__global__ __launch_bounds__(256) void prep_tw(ushort* __restrict__ tw) {
  int i = blockIdx.x * 256 + threadIdx.x;
  if (i >= 62592) return;
  float val = 0.f; int base, plane, e;
  if (i < 5760) {                      // TWF [80][72]: n=2kw+p cols, k=x
    e = i; base = TWF_OFF; plane = 5760;
    int n = e / 72, k = e % 72;
    if (n < 66 && k < 64) {
      int kw = n >> 1;
      float s, c; sincosf(TWOPI_64 * (float)((k * kw) & 63), &s, &c);
      val = (n & 1) ? -s : c;
    }
  } else if (i < 57984) {              // TWH[v] [128][136]
    int j = i - 5760; int v = j / 17408; e = j % 17408;
    base = TWH0_OFF + v * 34816; plane = 17408;
    float sgn = (v == 1) ? 1.f : -1.f;
    float scale = (v == 0) ? (1.f / 64.f) : 1.f;
    int n = e / 136, k = e % 136;
    if (k < 128) {
      int kh = n >> 1, q = n & 1, h = k >> 1, p = k & 1;
      float s, c; sincosf(TWOPI_64 * (float)((h * kh) & 63), &s, &c);
      val = (p == q) ? c : ((q == 1) ? sgn * s : -sgn * s);
      val *= scale;
    }
  } else {                             // TWI [64][72]: n=x, k=2kk+p
    e = i - 57984; base = TWI_OFF; plane = 4608;
    int n = e / 72, k = e % 72;
    if (k < 64) {
      int kk = k >> 1, p = k & 1;
      float w = (kk == 0) ? 1.f : 2.f;
      float s, c; sincosf(TWOPI_64 * (float)((n * kk) & 63), &s, &c);
      val = (p ? -s : c) * w * (1.f / 64.f);
    }
  }
  ushort h, l; split2(val, h, l);
  tw[base + e] = h; tw[base + plane + e] = l;
}

// ===================== real-activation GEMM (gate / proj) ==================
template <int MODE>   // 0: gate (silu) 1: proj
__global__ __launch_bounds__(256) void gemm_real(
    const float* __restrict__ act,
    const ushort* __restrict__ w_hi, const ushort* __restrict__ w_lo,
    const float* __restrict__ bias, float* __restrict__ outp) {
  __shared__ float raw[32 * 64];
  __shared__ ushort planeH[64 * 32];
  __shared__ ushort planeL[64 * 32];
  int b = blockIdx.z;
  int m0 = blockIdx.x * 64;
  int d0 = blockIdx.y * 64;
  int tid = threadIdx.x;
  int lane = tid & 63, wid = tid >> 6;
  int fr = lane & 15, fq = lane >> 4;
  int wm = wid & 1, wd = wid >> 1;
  int co = tid >> 6, tm = tid & 63;
  const float* actb = act + (size_t)b * CC * SS + m0;

  f32x4 acc[2][2] = {};

  for (int k0 = 0; k0 < CC; k0 += 32) {
#pragma unroll
    for (int i = 0; i < 2; ++i) {
      int e0 = (i * 256 + tid) * 4;
      int c = e0 >> 6, m = e0 & 63;
      gll16(actb + (size_t)(k0 + c) * SS + m, raw + (i * 256 + (tid & 192)) * 4);
    }
    __syncthreads();
    {
      ushort h[8], l[8];
#pragma unroll
      for (int j = 0; j < 8; ++j) split2(raw[(co * 8 + j) * 64 + tm], h[j], l[j]);
      int ch = ((co ^ (tm & 3)) * 8);
      ushort8 vh, vl;
#pragma unroll
      for (int j = 0; j < 8; ++j) { vh[j] = h[j]; vl[j] = l[j]; }
      *reinterpret_cast<ushort8*>(&planeH[tm * 32 + ch]) = vh;
      *reinterpret_cast<ushort8*>(&planeL[tm * 32 + ch]) = vl;
    }
    __syncthreads();
    bf16x8 wfh[2], wfl[2], afh[2], afl[2];
#pragma unroll
    for (int dt = 0; dt < 2; ++dt) {
      int d = d0 + wd * 32 + dt * 16 + fr;
      size_t wo = (size_t)d * CC + k0 + fq * 8;
      wfh[dt] = *reinterpret_cast<const bf16x8*>(&w_hi[wo]);
      wfl[dt] = *reinterpret_cast<const bf16x8*>(&w_lo[wo]);
    }
#pragma unroll
    for (int mt = 0; mt < 2; ++mt) {
      int m = wm * 32 + mt * 16 + fr;
      int ch = (fq ^ (m & 3)) * 8;
      afh[mt] = *reinterpret_cast<const bf16x8*>(&planeH[m * 32 + ch]);
      afl[mt] = *reinterpret_cast<const bf16x8*>(&planeL[m * 32 + ch]);
    }
#pragma unroll
    for (int mt = 0; mt < 2; ++mt)
#pragma unroll
      for (int dt = 0; dt < 2; ++dt) {
        acc[mt][dt] = MFMA16(afh[mt], wfh[dt], acc[mt][dt]);
        acc[mt][dt] = MFMA16(afh[mt], wfl[dt], acc[mt][dt]);
        acc[mt][dt] = MFMA16(afl[mt], wfh[dt], acc[mt][dt]);
      }
  }
#pragma unroll
  for (int mt = 0; mt < 2; ++mt)
#pragma unroll
    for (int dt = 0; dt < 2; ++dt) {
      int d = d0 + wd * 32 + dt * 16 + fr;
      float bs = bias[d];
      size_t ob = ((size_t)b * CC + d) * SS + m0 + wm * 32 + mt * 16 + fq * 4;
#pragma unroll
      for (int r = 0; r < 4; ++r) {
        float z = acc[mt][dt][r] + bs;
        if (MODE == 0) z = z / (1.f + __expf(-z));
        outp[ob + r] = z;
      }
    }
}

// ===================== complex-activation GEMM (qk / v) ====================
template <int MODE>   // 0: qk (conj(q)*k out) 1: v (conj(A)*v in-place)
__global__ __launch_bounds__(256) void gemm_cplx(
    const float2* __restrict__ X,
    const ushort* __restrict__ w1_hi, const ushort* __restrict__ w1_lo,
    const ushort* __restrict__ w2_hi, const ushort* __restrict__ w2_lo,
    float2* __restrict__ io) {
  __shared__ float raw[32 * 128];
  __shared__ ushort pRH[64 * 32];
  __shared__ ushort pRL[64 * 32];
  __shared__ ushort pIH[64 * 32];
  __shared__ ushort pIL[64 * 32];
  int b = blockIdx.z;
  int m0 = blockIdx.x * 64;
  int d0 = blockIdx.y * 64;
  int tid = threadIdx.x;
  int lane = tid & 63, wid = tid >> 6;
  int fr = lane & 15, fq = lane >> 4;
  int wm = wid & 1, wd = wid >> 1;
  int co = tid >> 6, tm = tid & 63;
  const float* actf = (const float*)(X + (size_t)b * CC * PP + m0);

  f32x4 acc[2][2][MODE == 0 ? 4 : 2] = {};

  for (int k0 = 0; k0 < CC; k0 += 32) {
#pragma unroll
    for (int i = 0; i < 4; ++i) {
      int e0 = (i * 256 + tid) * 4;
      int c = e0 >> 7, r128 = e0 & 127;
      gll16(actf + (size_t)(k0 + c) * PP * 2 + r128,
            raw + (i * 256 + (tid & 192)) * 4);
    }
    __syncthreads();
    {
      const float2* raw2 = (const float2*)raw;
      ushort rh[8], rl[8], ih[8], il[8];
#pragma unroll
      for (int j = 0; j < 8; ++j) {
        float2 v = raw2[(co * 8 + j) * 64 + tm];
        split2(v.x, rh[j], rl[j]);
        split2(v.y, ih[j], il[j]);
      }
      int ch = ((co ^ (tm & 3)) * 8);
      ushort8 vrh, vrl, vih, vil;
#pragma unroll
      for (int j = 0; j < 8; ++j) { vrh[j] = rh[j]; vrl[j] = rl[j]; vih[j] = ih[j]; vil[j] = il[j]; }
      *reinterpret_cast<ushort8*>(&pRH[tm * 32 + ch]) = vrh;
      *reinterpret_cast<ushort8*>(&pRL[tm * 32 + ch]) = vrl;
      *reinterpret_cast<ushort8*>(&pIH[tm * 32 + ch]) = vih;
      *reinterpret_cast<ushort8*>(&pIL[tm * 32 + ch]) = vil;
    }
    __syncthreads();
    bf16x8 w1h[2], w1l[2], w2h[2], w2l[2];
    bf16x8 arh[2], arl[2], aih[2], ail[2];
#pragma unroll
    for (int dt = 0; dt < 2; ++dt) {
      int d = d0 + wd * 32 + dt * 16 + fr;
      size_t wo = (size_t)d * CC + k0 + fq * 8;
      w1h[dt] = *reinterpret_cast<const bf16x8*>(&w1_hi[wo]);
      w1l[dt] = *reinterpret_cast<const bf16x8*>(&w1_lo[wo]);
      if (MODE == 0) {
        w2h[dt] = *reinterpret_cast<const bf16x8*>(&w2_hi[wo]);
        w2l[dt] = *reinterpret_cast<const bf16x8*>(&w2_lo[wo]);
      }
    }
#pragma unroll
    for (int mt = 0; mt < 2; ++mt) {
      int m = wm * 32 + mt * 16 + fr;
      int ch = (fq ^ (m & 3)) * 8;
      arh[mt] = *reinterpret_cast<const bf16x8*>(&pRH[m * 32 + ch]);
      arl[mt] = *reinterpret_cast<const bf16x8*>(&pRL[m * 32 + ch]);
      aih[mt] = *reinterpret_cast<const bf16x8*>(&pIH[m * 32 + ch]);
      ail[mt] = *reinterpret_cast<const bf16x8*>(&pIL[m * 32 + ch]);
    }
#pragma unroll
    for (int mt = 0; mt < 2; ++mt)
#pragma unroll
      for (int dt = 0; dt < 2; ++dt) {
        acc[mt][dt][0] = MFMA16(arh[mt], w1h[dt], acc[mt][dt][0]);
        acc[mt][dt][0] = MFMA16(arh[mt], w1l[dt], acc[mt][dt][0]);
        acc[mt][dt][0] = MFMA16(arl[mt], w1h[dt], acc[mt][dt][0]);
        acc[mt][dt][1] = MFMA16(aih[mt], w1h[dt], acc[mt][dt][1]);
        acc[mt][dt][1] = MFMA16(aih[mt], w1l[dt], acc[mt][dt][1]);
        acc[mt][dt][1] = MFMA16(ail[mt], w1h[dt], acc[mt][dt][1]);
        if (MODE == 0) {
          acc[mt][dt][2] = MFMA16(arh[mt], w2h[dt], acc[mt][dt][2]);
          acc[mt][dt][2] = MFMA16(arh[mt], w2l[dt], acc[mt][dt][2]);
          acc[mt][dt][2] = MFMA16(arl[mt], w2h[dt], acc[mt][dt][2]);
          acc[mt][dt][3] = MFMA16(aih[mt], w2h[dt], acc[mt][dt][3]);
          acc[mt][dt][3] = MFMA16(aih[mt], w2l[dt], acc[mt][dt][3]);
          acc[mt][dt][3] = MFMA16(ail[mt], w2h[dt], acc[mt][dt][3]);
        }
      }
  }
#pragma unroll
  for (int mt = 0; mt < 2; ++mt)
#pragma unroll
    for (int dt = 0; dt < 2; ++dt) {
      int d = d0 + wd * 32 + dt * 16 + fr;
      size_t ob = ((size_t)b * CC + d) * PP + m0 + wm * 32 + mt * 16 + fq * 4;
#pragma unroll
      for (int r = 0; r < 4; ++r) {
        if (MODE == 0) {
          float qr = acc[mt][dt][0][r], qi = acc[mt][dt][1][r];
          float kr = acc[mt][dt][2][r], ki = acc[mt][dt][3][r];
          io[ob + r] = make_float2(qr * kr + qi * ki, qr * ki - qi * kr);
        } else {
          float vr = acc[mt][dt][0][r], vi = acc[mt][dt][1][r];
          float2 a = io[ob + r];
          io[ob + r] = make_float2(a.x * vr + a.y * vi, a.x * vi - a.y * vr);
        }
      }
    }
}

// ===================== DFT-w forward: real rows -> interleaved complex =====
// rows M=262144 (64 f32 each, stride 64); out rows 66 f32 (stride 66).
__global__ __launch_bounds__(256) void dftw_fwd(
    const float* __restrict__ in, float* __restrict__ outf,
    const ushort* __restrict__ tw) {
  __shared__ __align__(16) ushort B[12288];   // hi [80][72], lo at +5760
  int tid = threadIdx.x;
  int lane = tid & 63, wid = tid >> 6;
  int fr = lane & 15, fq = lane >> 4;
#pragma unroll
  for (int i = 0; i < 6; ++i)
    gll16((const char*)tw + (i * 256 + tid) * 16,
          (char*)B + (i * 256 + (tid & 192)) * 16);
  __syncthreads();
  bf16x8 bh[5][2], bl[5][2];
#pragma unroll
  for (int nt = 0; nt < 5; ++nt)
#pragma unroll
    for (int ks = 0; ks < 2; ++ks) {
      int o = (nt * 16 + fr) * 72 + ks * 32 + fq * 8;
      bh[nt][ks] = *reinterpret_cast<const bf16x8*>(&B[o]);
      bl[nt][ks] = *reinterpret_cast<const bf16x8*>(&B[5760 + o]);
    }
  for (int chunk = blockIdx.x; chunk < 4096; chunk += gridDim.x) {
    int m0 = chunk * 64 + wid * 16;
    const float* rowp = in + (size_t)(m0 + fr) * 64;
    f32x4 acc[5] = {};
#pragma unroll
    for (int ks = 0; ks < 2; ++ks) {
      float4 v0 = *reinterpret_cast<const float4*>(rowp + ks * 32 + fq * 8);
      float4 v1 = *reinterpret_cast<const float4*>(rowp + ks * 32 + fq * 8 + 4);
      float f[8] = {v0.x, v0.y, v0.z, v0.w, v1.x, v1.y, v1.z, v1.w};
      bf16x8 ah, al; pack8(f, ah, al);
#pragma unroll
      for (int nt = 0; nt < 5; ++nt) {
        acc[nt] = MFMA16(ah, bh[nt][ks], acc[nt]);
        acc[nt] = MFMA16(ah, bl[nt][ks], acc[nt]);
        acc[nt] = MFMA16(al, bh[nt][ks], acc[nt]);
      }
    }
#pragma unroll
    for (int nt = 0; nt < 5; ++nt) {
      int n = nt * 16 + fr;
      if (n < 66) {
#pragma unroll
        for (int r = 0; r < 4; ++r) {
          int m = m0 + fq * 4 + r;
          outf[(size_t)m * 66 + n] = acc[nt][r];
        }
      }
    }
  }
}

// ===================== DFT-h: complex columns, IN-PLACE ====================
// rows M = (bc,kw) = 135168; A-row = 128 f32 along h (float2 stride WR).
__global__ __launch_bounds__(256) void dfth(
    float* __restrict__ io, const ushort* __restrict__ tw) {
  __shared__ __align__(16) ushort B[34816];   // hi [128][136], lo at +17408
  int tid = threadIdx.x;
  int lane = tid & 63, wid = tid >> 6;
  int fr = lane & 15, fq = lane >> 4;
#pragma unroll
  for (int i = 0; i < 17; ++i)
    gll16((const char*)tw + (i * 256 + tid) * 16,
          (char*)B + (i * 256 + (tid & 192)) * 16);
  __syncthreads();
  for (int chunk = blockIdx.x; chunk < 2112; chunk += gridDim.x) {
    int m0 = chunk * 64 + wid * 16;
    int rg = m0 + fr;
    int bc = rg / 33, kw = rg - bc * 33;
    const float* colp = io + ((size_t)bc * PP + kw) * 2;
    bf16x8 ah[4], al[4];
#pragma unroll
    for (int ks = 0; ks < 4; ++ks) {
      float f[8];
#pragma unroll
      for (int e = 0; e < 4; ++e) {
        float2 v = *reinterpret_cast<const float2*>(
            colp + (size_t)(ks * 16 + fq * 4 + e) * WR * 2);
        f[2 * e] = v.x; f[2 * e + 1] = v.y;
      }
      pack8(f, ah[ks], al[ks]);
    }
    f32x4 acc[8] = {};
#pragma unroll
    for (int ks = 0; ks < 4; ++ks)
#pragma unroll
      for (int nt = 0; nt < 8; ++nt) {
        int o = (nt * 16 + fr) * 136 + ks * 32 + fq * 8;
        bf16x8 wh = *reinterpret_cast<const bf16x8*>(&B[o]);
        bf16x8 wl = *reinterpret_cast<const bf16x8*>(&B[17408 + o]);
        acc[nt] = MFMA16(ah[ks], wh, acc[nt]);
        acc[nt] = MFMA16(ah[ks], wl, acc[nt]);
        acc[nt] = MFMA16(al[ks], wh, acc[nt]);
      }
#pragma unroll
    for (int r = 0; r < 4; ++r) {
      int m = m0 + fq * 4 + r;
      int bc2 = m / 33, kw2 = m - bc2 * 33;
      float* outp = io + ((size_t)bc2 * PP + kw2) * 2;
#pragma unroll
      for (int nt = 0; nt < 8; ++nt) {
        int n = nt * 16 + fr;
        int kh = n >> 1, q = n & 1;
        outp[(size_t)kh * WR * 2 + q] = acc[nt][r];
      }
    }
  }
}

// ===================== DFT-w inverse: interleaved complex -> real ==========
// rows M=262144 (66 f32, stride 66) -> real rows (64 f32, stride 64).
__global__ __launch_bounds__(256) void dftw_inv(
    const float* __restrict__ inf, float* __restrict__ out,
    const float* __restrict__ tmul, const ushort* __restrict__ tw) {
  __shared__ __align__(16) ushort B[10240];   // hi [64][72], lo at +4608
  int tid = threadIdx.x;
  int lane = tid & 63, wid = tid >> 6;
  int fr = lane & 15, fq = lane >> 4;
#pragma unroll
  for (int i = 0; i < 5; ++i)
    gll16((const char*)tw + (i * 256 + tid) * 16,
          (char*)B + (i * 256 + (tid & 192)) * 16);
  __syncthreads();
  bf16x8 bh[4][2], bl[4][2];
#pragma unroll
  for (int nt = 0; nt < 4; ++nt)
#pragma unroll
    for (int ks = 0; ks < 2; ++ks) {
      int o = (nt * 16 + fr) * 72 + ks * 32 + fq * 8;
      bh[nt][ks] = *reinterpret_cast<const bf16x8*>(&B[o]);
      bl[nt][ks] = *reinterpret_cast<const bf16x8*>(&B[4608 + o]);
    }
  for (int chunk = blockIdx.x; chunk < 4096; chunk += gridDim.x) {
    int m0 = chunk * 64 + wid * 16;
    const float* rowp = inf + (size_t)(m0 + fr) * 66;
    f32x4 acc[4] = {};
#pragma unroll
    for (int ks = 0; ks < 2; ++ks) {
      float f[8];
#pragma unroll
      for (int e = 0; e < 4; ++e) {
        float2 v = *reinterpret_cast<const float2*>(rowp + ks * 32 + fq * 8 + 2 * e);
        f[2 * e] = v.x; f[2 * e + 1] = v.y;
      }
      bf16x8 ah, al; pack8(f, ah, al);
#pragma unroll
      for (int nt = 0; nt < 4; ++nt) {
        acc[nt] = MFMA16(ah, bh[nt][ks], acc[nt]);
        acc[nt] = MFMA16(ah, bl[nt][ks], acc[nt]);
        acc[nt] = MFMA16(al, bh[nt][ks], acc[nt]);
      }
    }
#pragma unroll
    for (int r = 0; r < 4; ++r) {
      int m = m0 + fq * 4 + r;
      float fr32 = inf[(size_t)m * 66 + 64] * (1.f / 64.f);
#pragma unroll
      for (int nt = 0; nt < 4; ++nt) {
        int x = nt * 16 + fr;
        float res = acc[nt][r] + ((x & 1) ? -fr32 : fr32);
        size_t o = (size_t)m * 64 + x;
        if (tmul) res *= tmul[o];
        out[o] = res;
      }
    }
  }
}

// ========================= softmax over n per (b,c) ========================
__global__ __launch_bounds__(256) void softmax_n(float* __restrict__ a) {
  __shared__ float red[16];
  int bc = blockIdx.x;
  float* p = a + (size_t)bc * SS;
  int t = threadIdx.x;
  float m = -1e30f;
  for (int i = t; i < SS; i += 256) m = fmaxf(m, p[i]);
#pragma unroll
  for (int off = 32; off > 0; off >>= 1) m = fmaxf(m, __shfl_down(m, off));
  if ((t & 63) == 0) red[t >> 6] = m;
  __syncthreads();
  if (t == 0) red[0] = fmaxf(fmaxf(red[0], red[1]), fmaxf(red[2], red[3]));
  __syncthreads();
  m = red[0];
  float s = 0.f;
  for (int i = t; i < SS; i += 256) s += __expf(p[i] - m);
#pragma unroll
  for (int off = 32; off > 0; off >>= 1) s += __shfl_down(s, off);
  if ((t & 63) == 0) red[8 + (t >> 6)] = s;
  __syncthreads();
  if (t == 0) red[4] = red[8] + red[9] + red[10] + red[11];
  __syncthreads();
  float inv = 1.f / red[4];
  for (int i = t; i < SS; i += 256) p[i] = __expf(p[i] - m) * inv;
}

// ===========================================================================
extern "C" void kernel_launch(void* const* d_in, const int* in_sizes, int n_in,
                              void* d_out, int out_size, void* d_ws, size_t ws_size,
                              hipStream_t stream) {
  const float* x      = (const float*)d_in[0];
  const float* w_qkv  = (const float*)d_in[1];
  const float* w_gate = (const float*)d_in[2];
  const float* b_gate = (const float*)d_in[3];
  const float* w_proj = (const float*)d_in[4];
  const float* b_proj = (const float*)d_in[5];
  float* out = (float*)d_out;

  char* ws = (char*)d_ws;
  float*  T  = (float*)ws;                             // 67,108,864 B
  float2* W0 = (float2*)(ws + 67108864);               // 69,206,016 B
  float2* W1 = (float2*)(ws + 136314880);              // 69,206,016 B
  ushort* PL = (ushort*)(ws + 205520896);              //  7,340,032 B
  ushort* TW = (ushort*)(ws + 212860928);              //    253,952 B (end 213,114,880)
  float* W0f = (float*)W0;
  float* W1f = (float*)W1;

  dim3 gemmS(SS / 64, CC / 64, BB);
  dim3 gemmP(PP / 64, CC / 64, BB);

  // 0. pre-split weights + twiddles
  prep_w<<<1310720 / 256, 256, 0, stream>>>(w_qkv, w_gate, w_proj, PL);
  prep_tw<<<245, 256, 0, stream>>>(TW);
  // 1. gate: t = silu(x @ w_gate^T + b_gate)
  gemm_real<0><<<gemmS, 256, 0, stream>>>(x, PL + GATE_HI, PL + GATE_LO, b_gate, T);
  // 2-3. X = rfft2(x, ortho): w-pass unscaled -> W0, h-pass (fwd,1/64) in-place
  dftw_fwd<<<1024, 256, 0, stream>>>(x, W0f, TW + TWF_OFF);
  dfth<<<528, 256, 0, stream>>>(W0f, TW + TWH0_OFF);               // X in W0
  // 4. attnf = conj(q)*k
  gemm_cplx<0><<<gemmP, 256, 0, stream>>>(W0, PL + QKV_HI, PL + QKV_LO,
                                          PL + QKV_HI + CC * CC, PL + QKV_LO + CC * CC, W1);
  // 5-6. attn = irfft2(attnf, ortho) -> d_out
  dfth<<<528, 256, 0, stream>>>(W1f, TW + TWH1_OFF);
  dftw_inv<<<1024, 256, 0, stream>>>(W1f, out, nullptr, TW + TWI_OFF);
  // 7. softmax over n per (b,c)
  softmax_n<<<BB * CC, 256, 0, stream>>>(out);
  // 8-9. A = rfft2(attn), backward norm (unscaled)
  dftw_fwd<<<1024, 256, 0, stream>>>(out, W1f, TW + TWF_OFF);
  dfth<<<528, 256, 0, stream>>>(W1f, TW + TWH2_OFF);               // A in W1
  // 10. v-GEMM fused with yf = conj(A)*v (in place on W1)
  gemm_cplx<1><<<gemmP, 256, 0, stream>>>(W0, PL + QKV_HI + 2 * CC * CC, PL + QKV_LO + 2 * CC * CC,
                                          nullptr, nullptr, W1);
  // 11-12. y = irfft2(yf, ortho), fused (.* t) -> W0 (real)
  dfth<<<528, 256, 0, stream>>>(W1f, TW + TWH1_OFF);
  dftw_inv<<<1024, 256, 0, stream>>>(W1f, W0f, T, TW + TWI_OFF);
  // 13. out = (y .* t) @ w_proj^T + b_proj
  gemm_real<1><<<gemmS, 256, 0, stream>>>(W0f, PL + PROJ_HI, PL + PROJ_LO, b_proj, out);
}